// Round 3
// baseline (91.399 us; speedup 1.0000x reference)
//
#include <hip/hip_runtime.h>

// N=4096, PAIR=2, M=64, D=128, O=128, R=2, MAX_DEG=32
// h = relu(x @ (d*Wsum + W0) + (d*bsum + b0));  out[n] = h0 @ h1^T
//
// Round 2: operand-swapped MFMAs so both epilogues write contiguous 4-elem
// packs per lane (ds_write_b64 for h, dwordx4 for out). wfrag layout is
// unchanged (B-frag contents == transposed-A-frag contents for 16x16x32).
// Fix vs prior round: nontemporal builtins need ext_vector_type, not
// HIP_vector_type float4.

typedef __attribute__((ext_vector_type(8))) short bf16x8;
typedef __attribute__((ext_vector_type(4))) float f32x4;

__device__ __forceinline__ unsigned short f2bf(float f) {
    union { float f; unsigned u; } v; v.f = f;
    unsigned r = (v.u + 0x7fffu + ((v.u >> 16) & 1u)) >> 16;
    return (unsigned short)r;
}

__global__ __launch_bounds__(256) void build_weights(
    const float* __restrict__ W_r,  // [2,128,128]
    const float* __restrict__ b_r,  // [2,128]
    const float* __restrict__ W0,   // [128,128]
    const float* __restrict__ b0,   // [128]
    unsigned short* __restrict__ wfrag,  // [32*8*4*64*8]
    float* __restrict__ call)            // [32*128]
{
    int t = blockIdx.x * blockDim.x + threadIdx.x;   // 0..65535
    int lane = t & 63;
    int ks = (t >> 6) & 3;
    int ct = (t >> 8) & 7;
    int d  = (t >> 11) & 31;
    int o = ct * 16 + (lane & 15);
    int kbase = ks * 32 + (lane >> 4) * 8;
    unsigned short* dst = wfrag + (size_t)t * 8;
#pragma unroll
    for (int j = 0; j < 8; ++j) {
        int k = kbase + j;
        float wsum = W_r[k * 128 + o] + W_r[128 * 128 + k * 128 + o];
        float w = (float)d * wsum + W0[k * 128 + o];
        dst[j] = f2bf(w);
    }
    if (t < 32 * 128) {
        int dd = t >> 7, oo = t & 127;
        call[t] = (float)dd * (b_r[oo] + b_r[128 + oo]) + b0[oo];
    }
}

__global__ __launch_bounds__(256) void edge_kernel(
    const float* __restrict__ x,    // [N,2,64,128] f32
    const int* __restrict__ deg,    // [N]
    const unsigned short* __restrict__ wfrag,
    const float* __restrict__ call,
    float* __restrict__ out)        // [N,64,64] f32
{
    // h tile, bf16, XOR-swizzled: byte(row,col) = row*256 + (((col>>3)^(row&7))<<4) + (col&7)*2
    __shared__ unsigned short hlds[128 * 128];  // 32 KB

    const int n = blockIdx.x;
    const int tid = threadIdx.x;
    const int wave = tid >> 6;
    const int lane = tid & 63;
    const int l15 = lane & 15;
    const int lhi = lane >> 4;      // 0..3
    const int d = deg[n];

    const float* xn = x + (size_t)n * (2 * 64 * 128);
    const unsigned short* wf = wfrag + (size_t)d * (8 * 4 * 64 * 8);
    const float* cd = call + d * 128;

    // ---- load A-side fragments of X (this wave's 32 rows), fp32 -> bf16 ----
    // lane data: x[rbase + rt*16 + l15][ks*32 + lhi*8 + j]  (valid as A-frag or B-frag)
    const int rbase = wave * 32;
    bf16x8 afrag[2][4];
#pragma unroll
    for (int rt = 0; rt < 2; ++rt) {
        const float* rowp = xn + (size_t)(rbase + rt * 16 + l15) * 128;
#pragma unroll
        for (int ks = 0; ks < 4; ++ks) {
            const f32x4* p = (const f32x4*)(rowp + ks * 32 + lhi * 8);
            f32x4 a0 = __builtin_nontemporal_load(p);
            f32x4 a1 = __builtin_nontemporal_load(p + 1);
            bf16x8 f;
            f[0] = (short)f2bf(a0.x); f[1] = (short)f2bf(a0.y);
            f[2] = (short)f2bf(a0.z); f[3] = (short)f2bf(a0.w);
            f[4] = (short)f2bf(a1.x); f[5] = (short)f2bf(a1.y);
            f[6] = (short)f2bf(a1.z); f[7] = (short)f2bf(a1.w);
            afrag[rt][ks] = f;
        }
    }

    // ---- GEMM1 (swapped): D[o][m] = mfma(Wfrag as A, Xfrag as B) ----
    // lane holds o = ct*16 + lhi*4 + r (consecutive r), m = rbase + rt*16 + l15
#pragma unroll
    for (int ct = 0; ct < 8; ++ct) {
        bf16x8 bfrag[4];
#pragma unroll
        for (int ks = 0; ks < 4; ++ks)
            bfrag[ks] = *(const bf16x8*)(wf + ((size_t)(ct * 4 + ks) * 64 + lane) * 8);
        const f32x4 cc4 = *(const f32x4*)(cd + ct * 16 + lhi * 4);
#pragma unroll
        for (int rt = 0; rt < 2; ++rt) {
            f32x4 acc = {0.f, 0.f, 0.f, 0.f};
#pragma unroll
            for (int ks = 0; ks < 4; ++ks)
                acc = __builtin_amdgcn_mfma_f32_16x16x32_bf16(bfrag[ks], afrag[rt][ks], acc, 0, 0, 0);
            float h0v = acc[0] + cc4.x; h0v = h0v > 0.f ? h0v : 0.f;
            float h1v = acc[1] + cc4.y; h1v = h1v > 0.f ? h1v : 0.f;
            float h2v = acc[2] + cc4.z; h2v = h2v > 0.f ? h2v : 0.f;
            float h3v = acc[3] + cc4.w; h3v = h3v > 0.f ? h3v : 0.f;
            unsigned long long pack =
                  (unsigned long long)f2bf(h0v)
                | ((unsigned long long)f2bf(h1v) << 16)
                | ((unsigned long long)f2bf(h2v) << 32)
                | ((unsigned long long)f2bf(h3v) << 48);
            int m = rbase + rt * 16 + l15;
            int chunk = (ct * 2 + (lhi >> 1)) ^ (m & 7);
            int byteoff = m * 256 + chunk * 16 + (lhi & 1) * 8;
            *(unsigned long long*)((char*)hlds + byteoff) = pack;
        }
    }
    __syncthreads();

    // ---- GEMM2 (swapped): D[q][m] = mfma(h1frag as A, h0frag as B) ----
    // wave owns m-tile wave*16; loops q-tiles; store f32x4 (4 consecutive q)
    const int mrow = wave * 16 + l15;     // h0 row (= out row)
    bf16x8 hb[4];
#pragma unroll
    for (int ks = 0; ks < 4; ++ks) {
        int chunk = (ks * 4 + lhi) ^ (mrow & 7);
        hb[ks] = *(const bf16x8*)((const char*)hlds + mrow * 256 + chunk * 16);
    }
    float* outn = out + (size_t)n * 4096;
#pragma unroll
    for (int qt = 0; qt < 4; ++qt) {
        int qrow = 64 + qt * 16 + l15;    // h1 row (= out col base)
        f32x4 acc = {0.f, 0.f, 0.f, 0.f};
#pragma unroll
        for (int ks = 0; ks < 4; ++ks) {
            int chunk = (ks * 4 + lhi) ^ (qrow & 7);
            bf16x8 ha = *(const bf16x8*)((const char*)hlds + qrow * 256 + chunk * 16);
            acc = __builtin_amdgcn_mfma_f32_16x16x32_bf16(ha, hb[ks], acc, 0, 0, 0);
        }
        f32x4 o4 = {acc[0], acc[1], acc[2], acc[3]};
        __builtin_nontemporal_store(o4, (f32x4*)(outn + mrow * 64 + qt * 16 + lhi * 4));
    }
}

extern "C" void kernel_launch(void* const* d_in, const int* in_sizes, int n_in,
                              void* d_out, int out_size, void* d_ws, size_t ws_size,
                              hipStream_t stream) {
    const float* x   = (const float*)d_in[0];   // node_features [4096,2,64,128]
    const int*   deg = (const int*)d_in[1];     // [4096]
    const float* W_r = (const float*)d_in[2];   // [2,128,128]
    const float* b_r = (const float*)d_in[3];   // [2,128]
    const float* W0  = (const float*)d_in[4];   // [128,128]
    const float* b0  = (const float*)d_in[5];   // [128]
    float* out = (float*)d_out;                 // [4096,64,64]

    unsigned short* wfrag = (unsigned short*)d_ws;                    // 1 MB
    float* call = (float*)((unsigned short*)d_ws + 32 * 8 * 4 * 64 * 8); // +16 KB

    build_weights<<<256, 256, 0, stream>>>(W_r, b_r, W0, b0, wfrag, call);
    edge_kernel<<<4096, 256, 0, stream>>>(x, deg, wfrag, call, out);
}

// Round 4
// 81.356 us; speedup vs baseline: 1.1235x; 1.1235x over previous
//
#include <hip/hip_runtime.h>
#include <hip/hip_bf16.h>

// N=4096, PAIR=2, M=64, D=128, O=128, R=2, MAX_DEG=32
// h = relu(x @ (d*Wsum + W0) + (d*bsum + b0));  out[n] = h0 @ h1^T
//
// Round 3: Round-2 operand-swapped structure, minus nontemporal hints
// (suspected Round-2 regressor), plus HW packed bf16 conversion
// (v_cvt_pk_bf16_f32 via __float22bfloat162_rn) replacing the 4-op
// software f2bf on both the x-convert (64/thread) and h-epilogue
// (16/thread) paths.

typedef __attribute__((ext_vector_type(8))) short bf16x8;
typedef __attribute__((ext_vector_type(4))) float f32x4;

__device__ __forceinline__ unsigned int pkbf(float a, float b) {
    union { __hip_bfloat162 h; unsigned int u; } v;
    v.h = __float22bfloat162_rn(float2{a, b});
    return v.u;
}

__global__ __launch_bounds__(256) void build_weights(
    const float* __restrict__ W_r,  // [2,128,128]
    const float* __restrict__ b_r,  // [2,128]
    const float* __restrict__ W0,   // [128,128]
    const float* __restrict__ b0,   // [128]
    unsigned short* __restrict__ wfrag,  // [32*8*4*64*8]
    float* __restrict__ call)            // [32*128]
{
    int t = blockIdx.x * blockDim.x + threadIdx.x;   // 0..65535
    int lane = t & 63;
    int ks = (t >> 6) & 3;
    int ct = (t >> 8) & 7;
    int d  = (t >> 11) & 31;
    int o = ct * 16 + (lane & 15);
    int kbase = ks * 32 + (lane >> 4) * 8;
    unsigned int* dst = (unsigned int*)(wfrag + (size_t)t * 8);
#pragma unroll
    for (int j = 0; j < 4; ++j) {
        int k0 = kbase + 2 * j;
        float wA = (float)d * (W_r[k0 * 128 + o] + W_r[128 * 128 + k0 * 128 + o]) + W0[k0 * 128 + o];
        float wB = (float)d * (W_r[(k0 + 1) * 128 + o] + W_r[128 * 128 + (k0 + 1) * 128 + o]) + W0[(k0 + 1) * 128 + o];
        dst[j] = pkbf(wA, wB);
    }
    if (t < 32 * 128) {
        int dd = t >> 7, oo = t & 127;
        call[t] = (float)dd * (b_r[oo] + b_r[128 + oo]) + b0[oo];
    }
}

__global__ __launch_bounds__(256) void edge_kernel(
    const float* __restrict__ x,    // [N,2,64,128] f32
    const int* __restrict__ deg,    // [N]
    const unsigned short* __restrict__ wfrag,
    const float* __restrict__ call,
    float* __restrict__ out)        // [N,64,64] f32
{
    // h tile, bf16, XOR-swizzled: byte(row,col) = row*256 + (((col>>3)^(row&7))<<4) + (col&7)*2
    __shared__ unsigned short hlds[128 * 128];  // 32 KB

    const int n = blockIdx.x;
    const int tid = threadIdx.x;
    const int wave = tid >> 6;
    const int lane = tid & 63;
    const int l15 = lane & 15;
    const int lhi = lane >> 4;      // 0..3
    const int d = deg[n];

    const float* xn = x + (size_t)n * (2 * 64 * 128);
    const unsigned short* wf = wfrag + (size_t)d * (8 * 4 * 64 * 8);
    const float* cd = call + d * 128;

    // ---- load A-side fragments of X (this wave's 32 rows), fp32 -> bf16 ----
    // lane data: x[rbase + rt*16 + l15][ks*32 + lhi*8 + j]  (valid as A-frag or B-frag)
    const int rbase = wave * 32;
    bf16x8 afrag[2][4];
#pragma unroll
    for (int rt = 0; rt < 2; ++rt) {
        const float* rowp = xn + (size_t)(rbase + rt * 16 + l15) * 128;
#pragma unroll
        for (int ks = 0; ks < 4; ++ks) {
            const f32x4* p = (const f32x4*)(rowp + ks * 32 + lhi * 8);
            f32x4 a0 = p[0];
            f32x4 a1 = p[1];
            union { bf16x8 v; unsigned int u[4]; } f;
            f.u[0] = pkbf(a0.x, a0.y);
            f.u[1] = pkbf(a0.z, a0.w);
            f.u[2] = pkbf(a1.x, a1.y);
            f.u[3] = pkbf(a1.z, a1.w);
            afrag[rt][ks] = f.v;
        }
    }

    // ---- GEMM1 (swapped): D[o][m] = mfma(Wfrag as A, Xfrag as B) ----
    // lane holds o = ct*16 + lhi*4 + r (consecutive r), m = rbase + rt*16 + l15
#pragma unroll
    for (int ct = 0; ct < 8; ++ct) {
        bf16x8 bfrag[4];
#pragma unroll
        for (int ks = 0; ks < 4; ++ks)
            bfrag[ks] = *(const bf16x8*)(wf + ((size_t)(ct * 4 + ks) * 64 + lane) * 8);
        const f32x4 cc4 = *(const f32x4*)(cd + ct * 16 + lhi * 4);
#pragma unroll
        for (int rt = 0; rt < 2; ++rt) {
            f32x4 acc = {0.f, 0.f, 0.f, 0.f};
#pragma unroll
            for (int ks = 0; ks < 4; ++ks)
                acc = __builtin_amdgcn_mfma_f32_16x16x32_bf16(bfrag[ks], afrag[rt][ks], acc, 0, 0, 0);
            float h0v = fmaxf(acc[0] + cc4.x, 0.f);
            float h1v = fmaxf(acc[1] + cc4.y, 0.f);
            float h2v = fmaxf(acc[2] + cc4.z, 0.f);
            float h3v = fmaxf(acc[3] + cc4.w, 0.f);
            union { unsigned int u[2]; unsigned long long ull; } pk;
            pk.u[0] = pkbf(h0v, h1v);
            pk.u[1] = pkbf(h2v, h3v);
            int m = rbase + rt * 16 + l15;
            int chunk = (ct * 2 + (lhi >> 1)) ^ (m & 7);
            int byteoff = m * 256 + chunk * 16 + (lhi & 1) * 8;
            *(unsigned long long*)((char*)hlds + byteoff) = pk.ull;
        }
    }
    __syncthreads();

    // ---- GEMM2 (swapped): D[q][m] = mfma(h1frag as A, h0frag as B) ----
    // wave owns m-tile wave*16; loops q-tiles; store f32x4 (4 consecutive q)
    const int mrow = wave * 16 + l15;     // h0 row (= out row)
    bf16x8 hb[4];
#pragma unroll
    for (int ks = 0; ks < 4; ++ks) {
        int chunk = (ks * 4 + lhi) ^ (mrow & 7);
        hb[ks] = *(const bf16x8*)((const char*)hlds + mrow * 256 + chunk * 16);
    }
    float* outn = out + (size_t)n * 4096;
#pragma unroll
    for (int qt = 0; qt < 4; ++qt) {
        int qrow = 64 + qt * 16 + l15;    // h1 row (= out col base)
        f32x4 acc = {0.f, 0.f, 0.f, 0.f};
#pragma unroll
        for (int ks = 0; ks < 4; ++ks) {
            int chunk = (ks * 4 + lhi) ^ (qrow & 7);
            bf16x8 ha = *(const bf16x8*)((const char*)hlds + qrow * 256 + chunk * 16);
            acc = __builtin_amdgcn_mfma_f32_16x16x32_bf16(ha, hb[ks], acc, 0, 0, 0);
        }
        *(f32x4*)(outn + mrow * 64 + qt * 16 + lhi * 4) = acc;
    }
}

extern "C" void kernel_launch(void* const* d_in, const int* in_sizes, int n_in,
                              void* d_out, int out_size, void* d_ws, size_t ws_size,
                              hipStream_t stream) {
    const float* x   = (const float*)d_in[0];   // node_features [4096,2,64,128]
    const int*   deg = (const int*)d_in[1];     // [4096]
    const float* W_r = (const float*)d_in[2];   // [2,128,128]
    const float* b_r = (const float*)d_in[3];   // [2,128]
    const float* W0  = (const float*)d_in[4];   // [128,128]
    const float* b0  = (const float*)d_in[5];   // [128]
    float* out = (float*)d_out;                 // [4096,64,64]

    unsigned short* wfrag = (unsigned short*)d_ws;                    // 1 MB
    float* call = (float*)((unsigned short*)d_ws + 32 * 8 * 4 * 64 * 8); // +16 KB

    build_weights<<<256, 256, 0, stream>>>(W_r, b_r, W0, b0, wfrag, call);
    edge_kernel<<<4096, 256, 0, stream>>>(x, deg, wfrag, call, out);
}

// Round 5
// 76.489 us; speedup vs baseline: 1.1949x; 1.0636x over previous
//
#include <hip/hip_runtime.h>
#include <hip/hip_bf16.h>

// N=4096, PAIR=2, M=64, D=128, O=128, R=2, MAX_DEG=32
// h = relu(x @ (d*Wsum + W0) + (d*bsum + b0));  out[n] = h0 @ h1^T
//
// Round 5: stage wfrag[d] (32 KB) into LDS once per block (was: 4x redundant
// flat-global reads against a streaming-thrashed L2). GEMM1 reads B-frags via
// ds_read_b128. h reuses the SAME 32 KB LDS, o-tile-major ([ct][m][16col],
// 4 KB per ct == the wfrag[ct] region it replaces), with per-2-ct-phase
// barriers for the WAR hazard and a slot-XOR (s ^= (m>>2)&1) for bank spread.
// cc bias vectors are prefetched one phase ahead across the new barriers.

typedef __attribute__((ext_vector_type(8))) short bf16x8;
typedef __attribute__((ext_vector_type(4))) float f32x4;

__device__ __forceinline__ unsigned int pkbf(float a, float b) {
    union { __hip_bfloat162 h; unsigned int u; } v;
    v.h = __float22bfloat162_rn(float2{a, b});
    return v.u;
}

__global__ __launch_bounds__(256) void build_weights(
    const float* __restrict__ W_r,  // [2,128,128]
    const float* __restrict__ b_r,  // [2,128]
    const float* __restrict__ W0,   // [128,128]
    const float* __restrict__ b0,   // [128]
    unsigned short* __restrict__ wfrag,  // [32][8*4*64*8]  (32 KB per deg)
    float* __restrict__ call)            // [32*128]
{
    int t = blockIdx.x * blockDim.x + threadIdx.x;   // 0..65535
    int lane = t & 63;
    int ks = (t >> 6) & 3;
    int ct = (t >> 8) & 7;
    int d  = (t >> 11) & 31;
    int o = ct * 16 + (lane & 15);
    int kbase = ks * 32 + (lane >> 4) * 8;
    unsigned int* dst = (unsigned int*)(wfrag + (size_t)t * 8);
#pragma unroll
    for (int j = 0; j < 4; ++j) {
        int k0 = kbase + 2 * j;
        float wA = (float)d * (W_r[k0 * 128 + o] + W_r[128 * 128 + k0 * 128 + o]) + W0[k0 * 128 + o];
        float wB = (float)d * (W_r[(k0 + 1) * 128 + o] + W_r[128 * 128 + (k0 + 1) * 128 + o]) + W0[(k0 + 1) * 128 + o];
        dst[j] = pkbf(wA, wB);
    }
    if (t < 32 * 128) {
        int dd = t >> 7, oo = t & 127;
        call[t] = (float)dd * (b_r[oo] + b_r[128 + oo]) + b0[oo];
    }
}

__global__ __launch_bounds__(256) void edge_kernel(
    const float* __restrict__ x,    // [N,2,64,128] f32
    const int* __restrict__ deg,    // [N]
    const unsigned short* __restrict__ wfrag,
    const float* __restrict__ call,
    float* __restrict__ out)        // [N,64,64] f32
{
    __shared__ unsigned short hlds[16384];  // 32 KB: wfrag staging, then h
    char* const ldsb = (char*)hlds;

    const int n = blockIdx.x;
    const int tid = threadIdx.x;
    const int wave = tid >> 6;
    const int lane = tid & 63;
    const int l15 = lane & 15;
    const int lhi = lane >> 4;      // 0..3
    const int d = deg[n];

    const float* xn = x + (size_t)n * (2 * 64 * 128);
    const char* wsrc = (const char*)(wfrag + (size_t)d * (8 * 4 * 64 * 8));
    const float* cd = call + d * 128;

    // ---- issue wfrag staging loads (L2/L3, 32 KB, coalesced 4 KB/wave-instr) ----
    f32x4 wst[8];
#pragma unroll
    for (int i = 0; i < 8; ++i)
        wst[i] = *(const f32x4*)(wsrc + i * 4096 + tid * 16);

    // ---- issue x loads (HBM) and convert to bf16 A/B-side fragments ----
    // lane data: x[rbase + rt*16 + l15][ks*32 + lhi*8 + j]
    const int rbase = wave * 32;
    bf16x8 afrag[2][4];
    f32x4 xraw[2][4][2];
#pragma unroll
    for (int rt = 0; rt < 2; ++rt) {
        const float* rowp = xn + (size_t)(rbase + rt * 16 + l15) * 128;
#pragma unroll
        for (int ks = 0; ks < 4; ++ks) {
            const f32x4* p = (const f32x4*)(rowp + ks * 32 + lhi * 8);
            xraw[rt][ks][0] = p[0];
            xraw[rt][ks][1] = p[1];
        }
    }

    // ---- write wfrag staging to LDS (waits only the first 8 loads) ----
#pragma unroll
    for (int i = 0; i < 8; ++i)
        *(f32x4*)(ldsb + i * 4096 + tid * 16) = wst[i];

#pragma unroll
    for (int rt = 0; rt < 2; ++rt)
#pragma unroll
        for (int ks = 0; ks < 4; ++ks) {
            f32x4 a0 = xraw[rt][ks][0];
            f32x4 a1 = xraw[rt][ks][1];
            union { bf16x8 v; unsigned int u[4]; } f;
            f.u[0] = pkbf(a0.x, a0.y);
            f.u[1] = pkbf(a0.z, a0.w);
            f.u[2] = pkbf(a1.x, a1.y);
            f.u[3] = pkbf(a1.z, a1.w);
            afrag[rt][ks] = f.v;
        }

    __syncthreads();   // staging visible to all waves

    // ---- GEMM1 (swapped): D[o][m] = mfma(Wfrag, Xfrag); 4 phases x 2 ct ----
    // h layout: byte = ct*4096 + m*32 + slot*16 + sub, slot = s ^ ((m>>2)&1)
    f32x4 ccA = *(const f32x4*)(cd + 0 * 16 + lhi * 4);
    f32x4 ccB = *(const f32x4*)(cd + 1 * 16 + lhi * 4);
#pragma unroll
    for (int p = 0; p < 4; ++p) {
        const int ct0 = 2 * p, ct1 = 2 * p + 1;
        bf16x8 bf0[4], bf1[4];
#pragma unroll
        for (int ks = 0; ks < 4; ++ks) {
            bf0[ks] = *(const bf16x8*)(ldsb + ct0 * 4096 + ks * 1024 + lane * 16);
            bf1[ks] = *(const bf16x8*)(ldsb + ct1 * 4096 + ks * 1024 + lane * 16);
        }
        f32x4 acc0[2] = {{0.f,0.f,0.f,0.f},{0.f,0.f,0.f,0.f}};
        f32x4 acc1[2] = {{0.f,0.f,0.f,0.f},{0.f,0.f,0.f,0.f}};
#pragma unroll
        for (int ks = 0; ks < 4; ++ks) {
#pragma unroll
            for (int rt = 0; rt < 2; ++rt) {
                acc0[rt] = __builtin_amdgcn_mfma_f32_16x16x32_bf16(bf0[ks], afrag[rt][ks], acc0[rt], 0, 0, 0);
                acc1[rt] = __builtin_amdgcn_mfma_f32_16x16x32_bf16(bf1[ks], afrag[rt][ks], acc1[rt], 0, 0, 0);
            }
        }
        // prefetch next phase's bias across the barrier
        const int ctn = (p < 3) ? (2 * p + 2) : 0;
        f32x4 ccA_n = *(const f32x4*)(cd + ctn * 16 + lhi * 4);
        f32x4 ccB_n = *(const f32x4*)(cd + (ctn + 1) * 16 + lhi * 4);

        __syncthreads();   // all waves done reading wfrag[ct0,ct1]

#pragma unroll
        for (int rt = 0; rt < 2; ++rt) {
            const int m = rbase + rt * 16 + l15;
            const int slot = ((lhi >> 1) ^ ((m >> 2) & 1));
            {
                float h0v = fmaxf(acc0[rt][0] + ccA.x, 0.f);
                float h1v = fmaxf(acc0[rt][1] + ccA.y, 0.f);
                float h2v = fmaxf(acc0[rt][2] + ccA.z, 0.f);
                float h3v = fmaxf(acc0[rt][3] + ccA.w, 0.f);
                union { unsigned int u[2]; unsigned long long ull; } pk;
                pk.u[0] = pkbf(h0v, h1v);
                pk.u[1] = pkbf(h2v, h3v);
                *(unsigned long long*)(ldsb + ct0 * 4096 + m * 32 + slot * 16 + (lhi & 1) * 8) = pk.ull;
            }
            {
                float h0v = fmaxf(acc1[rt][0] + ccB.x, 0.f);
                float h1v = fmaxf(acc1[rt][1] + ccB.y, 0.f);
                float h2v = fmaxf(acc1[rt][2] + ccB.z, 0.f);
                float h3v = fmaxf(acc1[rt][3] + ccB.w, 0.f);
                union { unsigned int u[2]; unsigned long long ull; } pk;
                pk.u[0] = pkbf(h0v, h1v);
                pk.u[1] = pkbf(h2v, h3v);
                *(unsigned long long*)(ldsb + ct1 * 4096 + m * 32 + slot * 16 + (lhi & 1) * 8) = pk.ull;
            }
        }
        ccA = ccA_n;
        ccB = ccB_n;
    }
    __syncthreads();   // h fully visible

    // ---- GEMM2 (swapped): D[q][m] = mfma(h1frag, h0frag) ----
    // frag read: row r, k = ks*32 + lhi*8 + j -> ct = ks*2 + (lhi>>1),
    // slot s = (lhi&1) ^ ((r>>2)&1)
    const int mrow = wave * 16 + l15;     // h0 row (= out row)
    bf16x8 hb[4];
#pragma unroll
    for (int ks = 0; ks < 4; ++ks) {
        const int ct = ks * 2 + (lhi >> 1);
        const int s  = (lhi & 1) ^ ((mrow >> 2) & 1);
        hb[ks] = *(const bf16x8*)(ldsb + ct * 4096 + mrow * 32 + s * 16);
    }
    float* outn = out + (size_t)n * 4096;
#pragma unroll
    for (int qt = 0; qt < 4; ++qt) {
        const int qrow = 64 + qt * 16 + l15;    // h1 row (= out col base)
        f32x4 acc = {0.f, 0.f, 0.f, 0.f};
#pragma unroll
        for (int ks = 0; ks < 4; ++ks) {
            const int ct = ks * 2 + (lhi >> 1);
            const int s  = (lhi & 1) ^ ((qrow >> 2) & 1);
            bf16x8 ha = *(const bf16x8*)(ldsb + ct * 4096 + qrow * 32 + s * 16);
            acc = __builtin_amdgcn_mfma_f32_16x16x32_bf16(ha, hb[ks], acc, 0, 0, 0);
        }
        *(f32x4*)(outn + mrow * 64 + qt * 16 + lhi * 4) = acc;
    }
}

extern "C" void kernel_launch(void* const* d_in, const int* in_sizes, int n_in,
                              void* d_out, int out_size, void* d_ws, size_t ws_size,
                              hipStream_t stream) {
    const float* x   = (const float*)d_in[0];   // node_features [4096,2,64,128]
    const int*   deg = (const int*)d_in[1];     // [4096]
    const float* W_r = (const float*)d_in[2];   // [2,128,128]
    const float* b_r = (const float*)d_in[3];   // [2,128]
    const float* W0  = (const float*)d_in[4];   // [128,128]
    const float* b0  = (const float*)d_in[5];   // [128]
    float* out = (float*)d_out;                 // [4096,64,64]

    unsigned short* wfrag = (unsigned short*)d_ws;                    // 1 MB
    float* call = (float*)((unsigned short*)d_ws + 32 * 8 * 4 * 64 * 8); // +16 KB

    build_weights<<<256, 256, 0, stream>>>(W_r, b_r, W0, b0, wfrag, call);
    edge_kernel<<<4096, 256, 0, stream>>>(x, deg, wfrag, call, out);
}